// Round 4
// baseline (220.174 us; speedup 1.0000x reference)
//
#include <hip/hip_runtime.h>
#include <stdint.h>

typedef __bf16 bf16x8 __attribute__((ext_vector_type(8)));
typedef float floatx4 __attribute__((ext_vector_type(4)));
typedef float floatx4u __attribute__((ext_vector_type(4), aligned(4)));
typedef unsigned int u32x4 __attribute__((ext_vector_type(4)));
typedef unsigned short u16;
typedef unsigned int u32;

#define CIN   64
#define COUT  128
#define H_    1855
#define KNB   6
#define KTOT  448      // (1+KNB)*CIN
#define NSTEPS 14      // KTOT / 32

// Half-tile buffer: 16 hl rows x 4 s-slots; row = 1024+16 pad = 1040 B
// (B-frag b128 reads land 2-way on banks: 1040/4 mod 32 == 4).
// Only TWO buffers now (ping-pong) -> LDS = 33280 B -> 4 blocks/CU.
#define HROW   1040
#define HBUFSZ 16640   // 16 * HROW

// ws layout (bytes)
#define WP_OFF     ((size_t)H_ * 4096 * 2)                 // xt3: bf16 [h][4096]
#define CINV_OFF   (WP_OFF + (size_t)COUT * KTOT * 2)
#define ZERO_OFF   (CINV_OFF + 7424)                       // 256-B aligned zero page
#define SRCOFF_OFF (ZERO_OFF + 1024)                       // u32 [H][8] gather row offsets
#define DUMP_OFF   (SRCOFF_OFF + 59392)                    // 256-B dump page (OOB stores)
#define INVOFF 0xFFFFFFFFu

#define PIN4(v) asm volatile("" : "+v"(v))

typedef __attribute__((address_space(1))) unsigned int as1_u32;
typedef __attribute__((address_space(3))) unsigned int as3_u32;
static __device__ __forceinline__ void ld16_to_lds(const void* g, void* l) {
    __builtin_amdgcn_global_load_lds((const as1_u32*)g, (as3_u32*)l, 16, 0, 0);
}

static __device__ inline u16 f32_to_bf16(float f) {
    u32 u = __float_as_uint(f);
    u32 r = (u + 0x7FFFu + ((u >> 16) & 1u)) >> 16;
    return (u16)r;
}

// ---- K1 (fused): transpose x f32 [bc][h] -> xt3 bf16 [h][bc], plus
// weight-pack / inverse-counts / zero-page / gather-offset table in the
// blockIdx.y==64 stripe. Transpose tile is u32-packed (bc-pairs) so phase-2
// is 2 x ds_read_b64 + one 16-B store (was 8 x ds_read_u16).
__global__ __launch_bounds__(256) void k_prep(const float* __restrict__ x,
                                              const float* __restrict__ wc,
                                              const float* __restrict__ wn,
                                              const int* __restrict__ nbr,
                                              u16* __restrict__ xt3,
                                              u16* __restrict__ wp,
                                              float* __restrict__ cInvG,
                                              u32* __restrict__ zeroPg,
                                              u32* __restrict__ srcOff) {
    int tid = threadIdx.x;
    if (blockIdx.y == 64) {            // ---- pack stripe (29 blocks, strided)
        for (int tg = blockIdx.x * 256 + tid; tg < COUT * KTOT; tg += 29 * 256) {
            if (tg < 64) zeroPg[tg] = 0u;
            if (tg < H_) {
                int cnt = 1;
#pragma unroll
                for (int j = 0; j < KNB; ++j) cnt += (nbr[tg * KNB + j] >= 0) ? 1 : 0;
                cInvG[tg] = 1.0f / (float)cnt;
            }
            if (tg < H_ * 8) {
                int h = tg >> 3, s = tg & 7;
                u32 e;
                if (s == 0) e = (u32)h * 8192u;
                else if (s <= 6) {
                    int n = nbr[h * KNB + (s - 1)];
                    e = (n >= 0) ? (u32)n * 8192u : INVOFF;
                } else e = INVOFF;
                srcOff[tg] = e;
            }
            int o = tg / KTOT;
            int rem = tg - o * KTOT;
            int s = rem >> 6, c = rem & 63;
            float v = (s == 0) ? wc[o * CIN + c]
                               : wn[(o * CIN + c) * KNB + (s - 1)];
            wp[tg] = f32_to_bf16(v);
        }
        return;
    }
    // ---- transpose stripe: tile = u32 (bc even|odd packed), stride 34
    __shared__ u32 t32[64][34];
    int h0  = blockIdx.x * 64;
    int bc0 = blockIdx.y * 64;
    int lh = tid & 15;                 // h-quad (4 h per thread)
    int rq = tid >> 4;                 // 0..15 rowpair sub-index
    bool safe = (h0 + 64 <= H_);
#pragma unroll
    for (int it = 0; it < 2; ++it) {
        int rp = it * 16 + rq;         // rowpair 0..31 -> rows 2rp, 2rp+1
        size_t r0 = (size_t)(bc0 + rp * 2) * H_;
        size_t r1 = r0 + H_;
        int h = h0 + lh * 4;
        u32 p[4];
        if (safe) {
            floatx4u f0 = *(const floatx4u*)(x + r0 + h);
            floatx4u f1 = *(const floatx4u*)(x + r1 + h);
#pragma unroll
            for (int j = 0; j < 4; ++j)
                p[j] = (u32)f32_to_bf16(f0[j]) | ((u32)f32_to_bf16(f1[j]) << 16);
        } else {
#pragma unroll
            for (int j = 0; j < 4; ++j) {
                int hh = h + j;
                u16 a = 0, b = 0;
                if (hh < H_) { a = f32_to_bf16(x[r0 + hh]); b = f32_to_bf16(x[r1 + hh]); }
                p[j] = (u32)a | ((u32)b << 16);
            }
        }
#pragma unroll
        for (int j = 0; j < 4; ++j) t32[lh * 4 + j][rp] = p[j];
    }
    __syncthreads();
    int bg = tid & 7;                  // bc-octet
    int hb = tid >> 3;                 // 0..31
#pragma unroll
    for (int ii = 0; ii < 2; ++ii) {
        int hl = ii * 32 + hb;
        int hh = h0 + hl;
        uint2 qa = *(const uint2*)&t32[hl][bg * 4];
        uint2 qb = *(const uint2*)&t32[hl][bg * 4 + 2];
        u32x4 q = {qa.x, qa.y, qb.x, qb.y};
        if (hh < H_)
            *(u32x4*)(xt3 + (size_t)hh * 4096 + bc0 + bg * 8) = q;
    }
}

// ---- K3: main gather-GEMM, 4 blocks/CU single-round ----------------------
// grid = 928 = 29 h-supertiles x 32 b-pairs (XCD = blk&7). Block: 256 thr =
// 4 waves, M=32/wave. LDS = 2 half-tile buffers = 33280 B -> 4 blocks/CU ->
// ALL 928 blocks co-resident (one round; was 2 rounds at 2 blocks/CU).
// Depth-1 ping-pong: phase p computes half p from buf[p&1] while staging
// half p+1 into buf[(p+1)&1]. Epilogue = direct stores from acc (no LDS
// C-stage); 32 stores/lane, count kept exact via dump page so the VW(32)
// after pair-0 retires exactly the in-flight staging loads.
__global__ __launch_bounds__(256, 4) void k_main(const u16* __restrict__ xt3,
                                                 const u16* __restrict__ wp,
                                                 const float* __restrict__ bias,
                                                 const float* __restrict__ cInvG,
                                                 const u32* __restrict__ srcOff,
                                                 float* __restrict__ dump,
                                                 float* __restrict__ out) {
    __shared__ __align__(16) char LDS[2 * HBUFSZ];

    int tid  = threadIdx.x;
    int gbl  = blockIdx.x;
    int bp   = gbl & 31;          // b-pair; XCD = gbl&7
    int hs   = gbl >> 5;          // 0..28
    int b0   = bp * 2;
    int h0   = hs * 64;

    int lane = tid & 63;
    int wave = tid >> 6;          // 0..3
    int col  = lane & 15;
    int quad = lane >> 4;
    int m0w  = wave * 32;
    int lane16 = lane & 15;
    int ssub = lane >> 4;
    int bl   = lane16 >> 3;
    int chunk = lane16 & 7;

    const char* xb = (const char*)xt3;   // == d_ws base; all offsets relative

    // A fragments (weights): A[m=col][k=quad*8+j]; 112 regs, pinned.
    u32x4 afrag[2][NSTEPS];
#pragma unroll
    for (int mt = 0; mt < 2; ++mt) {
        int o = m0w + mt * 16 + col;
#pragma unroll
        for (int kk = 0; kk < NSTEPS; ++kk)
            afrag[mt][kk] = *(const u32x4*)(wp + o * KTOT + kk * 32 + quad * 8);
    }
#pragma unroll
    for (int mt = 0; mt < 2; ++mt)
#pragma unroll
        for (int kk = 0; kk < NSTEPS; ++kk)
            PIN4(afrag[mt][kk]);

    float biasv[2][4];
#pragma unroll
    for (int mt = 0; mt < 2; ++mt)
#pragma unroll
        for (int r = 0; r < 4; ++r)
            biasv[mt][r] = bias[m0w + mt * 16 + quad * 4 + r];

    float icv[4];
#pragma unroll
    for (int t = 0; t < 4; ++t) {
        int hic = h0 + t * 16 + col;
        icv[t] = cInvG[hic < H_ ? hic : 0];
    }

    // Per-lane staging byte-offsets offs[tile][sg][i]; wave stages hl rows
    // wave*4+i; each instr = 4 s-pieces (ssub) x 16 chunks.
    u32 colOff = (u32)((b0 + bl) * 128 + chunk * 16);
    u32 zOff   = (u32)ZERO_OFF + (u32)(lane16 * 16);
    u32 offs[4][2][4];
#pragma unroll
    for (int t = 0; t < 4; ++t)
#pragma unroll
        for (int sg = 0; sg < 2; ++sg)
#pragma unroll
            for (int i = 0; i < 4; ++i) {
                int hh = h0 + t * 16 + wave * 4 + i;
                int s  = sg * 4 + ssub;
                u32 e = (hh < H_) ? srcOff[hh * 8 + s] : INVOFF;
                offs[t][sg][i] = (e == INVOFF) ? zOff : (e + colOff);
            }

    int rb0 = col * HROW + quad * 16;
    int rb1 = rb0 + 128;
    char* buf0 = LDS;
    char* buf1 = LDS + HBUFSZ;
    bool bnd = (hs == 28);

#define SGH(t, sg, bufp) do {                                                 \
    char* _d = (bufp) + (wave * 4) * HROW;                                    \
    _Pragma("unroll")                                                         \
    for (int _i = 0; _i < 4; ++_i)                                            \
        ld16_to_lds(xb + offs[t][sg][_i], _d + _i * HROW);                    \
} while (0)

#define CA(accv, bufp) do {  /* k-steps 0..7, zero-init */                    \
    _Pragma("unroll") for (int _m = 0; _m < 2; ++_m)                          \
    _Pragma("unroll") for (int _n = 0; _n < 2; ++_n)                          \
        accv[_m][_n] = (floatx4){0.0f, 0.0f, 0.0f, 0.0f};                     \
    __builtin_amdgcn_s_setprio(1);                                            \
    _Pragma("unroll")                                                         \
    for (int kk = 0; kk < 8; ++kk) {                                          \
        int koff = (kk >> 1) * 256 + (kk & 1) * 64;                           \
        bf16x8 bfa = *(const bf16x8*)((bufp) + rb0 + koff);                   \
        bf16x8 bfb = *(const bf16x8*)((bufp) + rb1 + koff);                   \
        bf16x8 a0 = __builtin_bit_cast(bf16x8, afrag[0][kk]);                 \
        bf16x8 a1 = __builtin_bit_cast(bf16x8, afrag[1][kk]);                 \
        accv[0][0] = __builtin_amdgcn_mfma_f32_16x16x32_bf16(a0, bfa, accv[0][0], 0, 0, 0); \
        accv[1][0] = __builtin_amdgcn_mfma_f32_16x16x32_bf16(a1, bfa, accv[1][0], 0, 0, 0); \
        accv[0][1] = __builtin_amdgcn_mfma_f32_16x16x32_bf16(a0, bfb, accv[0][1], 0, 0, 0); \
        accv[1][1] = __builtin_amdgcn_mfma_f32_16x16x32_bf16(a1, bfb, accv[1][1], 0, 0, 0); \
    }                                                                         \
    __builtin_amdgcn_s_setprio(0);                                            \
} while (0)

#define CB(accv, bufp) do {  /* k-steps 8..13, accumulate */                  \
    __builtin_amdgcn_s_setprio(1);                                            \
    _Pragma("unroll")                                                         \
    for (int kk = 8; kk < 14; ++kk) {                                         \
        int koff = ((kk - 8) >> 1) * 256 + (kk & 1) * 64;                     \
        bf16x8 bfa = *(const bf16x8*)((bufp) + rb0 + koff);                   \
        bf16x8 bfb = *(const bf16x8*)((bufp) + rb1 + koff);                   \
        bf16x8 a0 = __builtin_bit_cast(bf16x8, afrag[0][kk]);                 \
        bf16x8 a1 = __builtin_bit_cast(bf16x8, afrag[1][kk]);                 \
        accv[0][0] = __builtin_amdgcn_mfma_f32_16x16x32_bf16(a0, bfa, accv[0][0], 0, 0, 0); \
        accv[1][0] = __builtin_amdgcn_mfma_f32_16x16x32_bf16(a1, bfa, accv[1][0], 0, 0, 0); \
        accv[0][1] = __builtin_amdgcn_mfma_f32_16x16x32_bf16(a0, bfb, accv[0][1], 0, 0, 0); \
        accv[1][1] = __builtin_amdgcn_mfma_f32_16x16x32_bf16(a1, bfb, accv[1][1], 0, 0, 0); \
    }                                                                         \
    __builtin_amdgcn_s_setprio(0);                                            \
} while (0)

// Direct-store pair epilogue (no LDS). Per (nt,mt,r): the two t-substores
// are adjacent 64-B halves of one 128-B span, issued back-to-back -> L2
// write-merge. Store count per lane = 32 ALWAYS (dump page for the one
// ragged lane at h=1855) so the vmcnt ladder stays exact.
#define EPI(pp, a0v, a1v, BND) do {                                           \
    int _hl = h0 + (pp) * 32 + col;                                           \
    float _il = icv[(pp) * 2], _ih = icv[(pp) * 2 + 1];                       \
    _Pragma("unroll") for (int _nt = 0; _nt < 2; ++_nt)                       \
    _Pragma("unroll") for (int _mt = 0; _mt < 2; ++_mt)                       \
    _Pragma("unroll") for (int _r = 0; _r < 4; ++_r) {                        \
        int _o = m0w + _mt * 16 + quad * 4 + _r;                              \
        float* _d0 = out + (size_t)(b0 + _nt) * ((size_t)COUT * H_)           \
                   + (size_t)_o * H_ + _hl;                                   \
        float* _d1 = _d0 + 16;                                                \
        if ((BND) && (_hl + 16 >= H_)) _d1 = dump + lane;                     \
        *_d0 = a0v[_mt][_nt][_r] * _il + biasv[_mt][_r];                      \
        *_d1 = a1v[_mt][_nt][_r] * _ih + biasv[_mt][_r];                      \
    }                                                                         \
} while (0)

#define VW(n)  asm volatile("s_waitcnt vmcnt(" #n ") lgkmcnt(0)" ::: "memory")
#define BAR()  __builtin_amdgcn_s_barrier()

    floatx4 acc0[2][2], acc1[2][2];

    SGH(0, 0, buf0);                                   // L0 (half0)
    VW(0);  BAR(); SGH(0, 1, buf1); CA(acc0, buf0);    // ph0: half0, stage half1
    VW(0);  BAR(); SGH(1, 0, buf0); CB(acc0, buf1);    // ph1: half1, stage half2
    VW(0);  BAR(); SGH(1, 1, buf1); CA(acc1, buf0);    // ph2: half2, stage half3
    VW(0);  BAR(); SGH(2, 0, buf0); CB(acc1, buf1);    // ph3: half3, stage half4
    EPI(0, acc0, acc1, false);                         //  pair0 -> +32 stores
    VW(32); BAR(); SGH(2, 1, buf1); CA(acc0, buf0);    // ph4: retire L4 only
    VW(0);  BAR(); SGH(3, 0, buf0); CB(acc0, buf1);    // ph5: stores ~2 ph old
    VW(0);  BAR(); SGH(3, 1, buf1); CA(acc1, buf0);    // ph6
    VW(0);  BAR();                  CB(acc1, buf1);    // ph7
    EPI(1, acc0, acc1, bnd);                           //  pair1; drains at end

#undef SGH
#undef CA
#undef CB
#undef EPI
#undef VW
#undef BAR
}

extern "C" void kernel_launch(void* const* d_in, const int* in_sizes, int n_in,
                              void* d_out, int out_size, void* d_ws, size_t ws_size,
                              hipStream_t stream) {
    const float* x    = (const float*)d_in[0];   // f32 [64,64,1855]
    const int*   nbr  = (const int*)d_in[1];     // int32 [1855,6]
    const float* wc   = (const float*)d_in[2];   // f32 [128,64]
    const float* wn   = (const float*)d_in[3];   // f32 [128,64,6]
    const float* bias = (const float*)d_in[4];   // f32 [128]

    u16*   xt3    = (u16*)d_ws;
    u16*   wp     = (u16*)((char*)d_ws + WP_OFF);
    float* cInvG  = (float*)((char*)d_ws + CINV_OFF);
    u32*   zeroPg = (u32*)((char*)d_ws + ZERO_OFF);
    u32*   srcOff = (u32*)((char*)d_ws + SRCOFF_OFF);
    float* dump   = (float*)((char*)d_ws + DUMP_OFF);

    k_prep<<<dim3(29, 65), dim3(256), 0, stream>>>(
        x, wc, wn, nbr, xt3, wp, cInvG, zeroPg, srcOff);
    k_main<<<dim3(928), dim3(256), 0, stream>>>(
        xt3, wp, bias, cInvG, srcOff, dump, (float*)d_out);
}

// Round 6
// 144.065 us; speedup vs baseline: 1.5283x; 1.5283x over previous
//
#include <hip/hip_runtime.h>
#include <stdint.h>

typedef __bf16 bf16x8 __attribute__((ext_vector_type(8)));
typedef float floatx4 __attribute__((ext_vector_type(4)));
typedef float floatx4u __attribute__((ext_vector_type(4), aligned(4)));
typedef unsigned int u32x4 __attribute__((ext_vector_type(4)));
typedef unsigned short u16;
typedef unsigned int u32;

#define CIN   64
#define COUT  128
#define H_    1855
#define KNB   6
#define KTOT  448      // (1+KNB)*CIN
#define NSTEPS 14      // KTOT / 32

// N=64 half-tile buffer: 16 hl rows; row = [bhalf:2][s:4][b:2][c:64] = 2048 B
// + 16 pad = 2064 (b128 reads: word = 4*col+4*quad (+16) mod 32 — proven
// R1/R3 profile, ~1.8k conflict-cyc/block). Two ping-pong buffers = 66048 B
// -> 2 blocks/CU (the max this register budget allows; see R2/R4 post-mortems).
#define HROW   2064
#define HBUFSZ 33024   // 16 * HROW

// ws layout (bytes)
#define WP_OFF     ((size_t)H_ * 4096 * 2)                 // xt3: bf16 [h][4096]
#define CINV_OFF   (WP_OFF + (size_t)COUT * KTOT * 2)
#define ZERO_OFF   (CINV_OFF + 7424)                       // 512-B zero page (256-B aligned)
#define SRCOFF_OFF (ZERO_OFF + 1024)                       // u32 [H][8] gather row offsets
#define INVOFF 0xFFFFFFFFu

#define PIN4(v) asm volatile("" : "+v"(v))

typedef __attribute__((address_space(1))) unsigned int as1_u32;
typedef __attribute__((address_space(3))) unsigned int as3_u32;
static __device__ __forceinline__ void ld16_to_lds(const void* g, void* l) {
    __builtin_amdgcn_global_load_lds((const as1_u32*)g, (as3_u32*)l, 16, 0, 0);
}

static __device__ inline u16 f32_to_bf16(float f) {
    u32 u = __float_as_uint(f);
    u32 r = (u + 0x7FFFu + ((u >> 16) & 1u)) >> 16;
    return (u16)r;
}

// ---- K1 (fused): transpose x f32 [bc][h] -> xt3 bf16 [h][bc], plus
// weight-pack / inverse-counts / zero-page / gather-offset table in the
// blockIdx.y==64 stripe. u32-packed transpose tile (verified R3/R4).
__global__ __launch_bounds__(256) void k_prep(const float* __restrict__ x,
                                              const float* __restrict__ wc,
                                              const float* __restrict__ wn,
                                              const int* __restrict__ nbr,
                                              u16* __restrict__ xt3,
                                              u16* __restrict__ wp,
                                              float* __restrict__ cInvG,
                                              u32* __restrict__ zeroPg,
                                              u32* __restrict__ srcOff) {
    int tid = threadIdx.x;
    if (blockIdx.y == 64) {            // ---- pack stripe (29 blocks, strided)
        for (int tg = blockIdx.x * 256 + tid; tg < COUT * KTOT; tg += 29 * 256) {
            if (tg < 128) zeroPg[tg] = 0u;           // 512-B zero page
            if (tg < H_) {
                int cnt = 1;
#pragma unroll
                for (int j = 0; j < KNB; ++j) cnt += (nbr[tg * KNB + j] >= 0) ? 1 : 0;
                cInvG[tg] = 1.0f / (float)cnt;
            }
            if (tg < H_ * 8) {
                int h = tg >> 3, s = tg & 7;
                u32 e;
                if (s == 0) e = (u32)h * 8192u;
                else if (s <= 6) {
                    int n = nbr[h * KNB + (s - 1)];
                    e = (n >= 0) ? (u32)n * 8192u : INVOFF;
                } else e = INVOFF;
                srcOff[tg] = e;
            }
            int o = tg / KTOT;
            int rem = tg - o * KTOT;
            int s = rem >> 6, c = rem & 63;
            float v = (s == 0) ? wc[o * CIN + c]
                               : wn[(o * CIN + c) * KNB + (s - 1)];
            wp[tg] = f32_to_bf16(v);
        }
        return;
    }
    // ---- transpose stripe: tile = u32 (bc even|odd packed), stride 34
    __shared__ u32 t32[64][34];
    int h0  = blockIdx.x * 64;
    int bc0 = blockIdx.y * 64;
    int lh = tid & 15;                 // h-quad (4 h per thread)
    int rq = tid >> 4;                 // 0..15 rowpair sub-index
    bool safe = (h0 + 64 <= H_);
#pragma unroll
    for (int it = 0; it < 2; ++it) {
        int rp = it * 16 + rq;         // rowpair 0..31 -> rows 2rp, 2rp+1
        size_t r0 = (size_t)(bc0 + rp * 2) * H_;
        size_t r1 = r0 + H_;
        int h = h0 + lh * 4;
        u32 p[4];
        if (safe) {
            floatx4u f0 = *(const floatx4u*)(x + r0 + h);
            floatx4u f1 = *(const floatx4u*)(x + r1 + h);
#pragma unroll
            for (int j = 0; j < 4; ++j)
                p[j] = (u32)f32_to_bf16(f0[j]) | ((u32)f32_to_bf16(f1[j]) << 16);
        } else {
#pragma unroll
            for (int j = 0; j < 4; ++j) {
                int hh = h + j;
                u16 a = 0, b = 0;
                if (hh < H_) { a = f32_to_bf16(x[r0 + hh]); b = f32_to_bf16(x[r1 + hh]); }
                p[j] = (u32)a | ((u32)b << 16);
            }
        }
#pragma unroll
        for (int j = 0; j < 4; ++j) t32[lh * 4 + j][rp] = p[j];
    }
    __syncthreads();
    int bg = tid & 7;                  // bc-octet
    int hb = tid >> 3;                 // 0..31
#pragma unroll
    for (int ii = 0; ii < 2; ++ii) {
        int hl = ii * 32 + hb;
        int hh = h0 + hl;
        uint2 qa = *(const uint2*)&t32[hl][bg * 4];
        uint2 qb = *(const uint2*)&t32[hl][bg * 4 + 2];
        u32x4 q = {qa.x, qa.y, qb.x, qb.y};
        if (hh < H_)
            *(u32x4*)(xt3 + (size_t)hh * 4096 + bc0 + bg * 8) = q;
    }
}

// ---- K3: main gather-GEMM, N=64 single-round -----------------------------
// grid = 464 = 29 h-supertiles x 16 b-quads (<= 512 resident slots at
// 2 blocks/CU -> ONE residency round). Block: 256 thr = 4 waves, M=32/wave,
// tile N = 16 h x 4 b, K=448 in two halves (s0-3 | s4-6+pad). 8 phases,
// per-phase: 8 staging loads/wave + 8 MFMA/k-step (2x R3's compute per
// latency exposure). Registers ~215 unified <= 256 cap of (256,2) — do NOT
// raise min-waves (R2/R4 spill disasters).
__global__ __launch_bounds__(256, 2) void k_main(const u16* __restrict__ xt3,
                                                 const u16* __restrict__ wp,
                                                 const float* __restrict__ bias,
                                                 const float* __restrict__ cInvG,
                                                 const u32* __restrict__ srcOff,
                                                 float* __restrict__ out) {
    __shared__ __align__(16) char LDS[2 * HBUFSZ];

    int tid  = threadIdx.x;
    int gbl  = blockIdx.x;
    int bq   = gbl & 15;          // b-quad; XCD = gbl&7
    int hs   = gbl >> 4;          // 0..28
    int b0   = bq * 4;
    int h0   = hs * 64;

    int lane = tid & 63;
    int wave = tid >> 6;          // 0..3
    int col  = lane & 15;
    int quad = lane >> 4;
    int m0w  = wave * 32;
    int lane16 = lane & 15;
    int ssub = lane >> 4;         // s sub-index within a staging instr
    int bl   = lane16 >> 3;       // b low bit
    int chunk = lane16 & 7;       // 16-B c-chunk

    const char* xb = (const char*)xt3;   // == d_ws base; all offsets relative

    // A fragments (weights): A[m=col][k=quad*8+j]; 112 regs, pinned.
    u32x4 afrag[2][NSTEPS];
#pragma unroll
    for (int mt = 0; mt < 2; ++mt) {
        int o = m0w + mt * 16 + col;
#pragma unroll
        for (int kk = 0; kk < NSTEPS; ++kk)
            afrag[mt][kk] = *(const u32x4*)(wp + o * KTOT + kk * 32 + quad * 8);
    }
#pragma unroll
    for (int mt = 0; mt < 2; ++mt)
#pragma unroll
        for (int kk = 0; kk < NSTEPS; ++kk)
            PIN4(afrag[mt][kk]);

    float biasv[2][4];
#pragma unroll
    for (int mt = 0; mt < 2; ++mt)
#pragma unroll
        for (int r = 0; r < 4; ++r)
            biasv[mt][r] = bias[m0w + mt * 16 + quad * 4 + r];

    float icv[4];
#pragma unroll
    for (int t = 0; t < 4; ++t) {
        int hic = h0 + t * 16 + col;
        icv[t] = cInvG[hic < H_ ? hic : 0];
    }

    // Per-lane staging row-offsets offs[tile][hf][hl]: e = srcOff row byte
    // offset for (hh = h0+t*16+wave*4+hl, s = hf*4+ssub) plus the lane's
    // column slice; the bhalf term (+0/+256) is added at issue. Invalid ->
    // zero page (reads stay within its 512 B for either bhalf).
    u32 colOff = (u32)((b0 + bl) * 128 + chunk * 16);
    u32 zOff   = (u32)ZERO_OFF + (u32)(lane16 * 16);
    u32 offs[4][2][4];
#pragma unroll
    for (int t = 0; t < 4; ++t)
#pragma unroll
        for (int hf = 0; hf < 2; ++hf)
#pragma unroll
            for (int i = 0; i < 4; ++i) {
                int hh = h0 + t * 16 + wave * 4 + i;
                int s  = hf * 4 + ssub;
                u32 e = (hh < H_) ? srcOff[hh * 8 + s] : INVOFF;
                offs[t][hf][i] = (e == INVOFF) ? zOff : (e + colOff);
            }

    int rb = col * HROW + quad * 16;
    char* buf0 = LDS;
    char* buf1 = LDS + HBUFSZ;
    bool bnd = (hs == 28);

// Stage half-tile (t, hf) into bufp: 8 instrs = 4 hl rows x 2 bhalf.
// Dest = row base + bhalf*1024 (+ lane*16 implicit): [bhalf][s][b][c] layout.
// Global src = row offset (per-lane s) + bhalf*256 within the 512-B row slice.
#define SGH(t, hf, bufp) do {                                                 \
    _Pragma("unroll")                                                         \
    for (int _j = 0; _j < 8; ++_j) {                                          \
        int _hl = _j >> 1, _bh = _j & 1;                                      \
        ld16_to_lds(xb + offs[t][hf][_hl] + _bh * 256,                        \
                    (bufp) + (wave * 4 + _hl) * HROW + _bh * 1024);           \
    }                                                                         \
} while (0)

// B-frag byte offset for (kk2 local k-step, nt): bhalf = nt>>1 (+1024),
// s_local = kk2>>1 (+256), b low = nt&1 (+128), c half = kk&1 (+64), quad*16.
#define CA(accv, bufp) do {  /* k-steps 0..7 (s0..3), zero-init */            \
    _Pragma("unroll") for (int _m = 0; _m < 2; ++_m)                          \
    _Pragma("unroll") for (int _n = 0; _n < 4; ++_n)                          \
        accv[_m][_n] = (floatx4){0.0f, 0.0f, 0.0f, 0.0f};                     \
    __builtin_amdgcn_s_setprio(1);                                            \
    _Pragma("unroll")                                                         \
    for (int kk = 0; kk < 8; ++kk) {                                          \
        int _ko = (kk >> 1) * 256 + (kk & 1) * 64;                            \
        bf16x8 a0 = __builtin_bit_cast(bf16x8, afrag[0][kk]);                 \
        bf16x8 a1 = __builtin_bit_cast(bf16x8, afrag[1][kk]);                 \
        _Pragma("unroll")                                                     \
        for (int _n = 0; _n < 4; ++_n) {                                      \
            bf16x8 bf = *(const bf16x8*)((bufp) + rb + (_n >> 1) * 1024       \
                                         + (_n & 1) * 128 + _ko);             \
            accv[0][_n] = __builtin_amdgcn_mfma_f32_16x16x32_bf16(a0, bf, accv[0][_n], 0, 0, 0); \
            accv[1][_n] = __builtin_amdgcn_mfma_f32_16x16x32_bf16(a1, bf, accv[1][_n], 0, 0, 0); \
        }                                                                     \
    }                                                                         \
    __builtin_amdgcn_s_setprio(0);                                            \
} while (0)

#define CB(accv, bufp) do {  /* k-steps 8..13 (s4..6), accumulate */          \
    __builtin_amdgcn_s_setprio(1);                                            \
    _Pragma("unroll")                                                         \
    for (int kk = 8; kk < 14; ++kk) {                                         \
        int _k2 = kk - 8;                                                     \
        int _ko = (_k2 >> 1) * 256 + (_k2 & 1) * 64;                          \
        bf16x8 a0 = __builtin_bit_cast(bf16x8, afrag[0][kk]);                 \
        bf16x8 a1 = __builtin_bit_cast(bf16x8, afrag[1][kk]);                 \
        _Pragma("unroll")                                                     \
        for (int _n = 0; _n < 4; ++_n) {                                      \
            bf16x8 bf = *(const bf16x8*)((bufp) + rb + (_n >> 1) * 1024       \
                                         + (_n & 1) * 128 + _ko);             \
            accv[0][_n] = __builtin_amdgcn_mfma_f32_16x16x32_bf16(a0, bf, accv[0][_n], 0, 0, 0); \
            accv[1][_n] = __builtin_amdgcn_mfma_f32_16x16x32_bf16(a1, bf, accv[1][_n], 0, 0, 0); \
        }                                                                     \
    }                                                                         \
    __builtin_amdgcn_s_setprio(0);                                            \
} while (0)

// Per-tile epilogue: 32 direct stores/lane (16 consecutive col lanes = 64-B
// segments). Only the FINAL epilogue (uncounted, drains at endpgm) may mask
// the single ragged lane (hs==28, t==3, col==15) — counted ladder stays exact.
#define EPI(t, accv, BND) do {                                                \
    int _h = h0 + (t) * 16 + col;                                             \
    float _ic = icv[t];                                                       \
    bool _hv = !(BND) || (_h < H_);                                           \
    _Pragma("unroll") for (int _n = 0; _n < 4; ++_n)                          \
    _Pragma("unroll") for (int _m = 0; _m < 2; ++_m)                          \
    _Pragma("unroll") for (int _r = 0; _r < 4; ++_r) {                        \
        int _o = m0w + _m * 16 + quad * 4 + _r;                               \
        float _v = accv[_m][_n][_r] * _ic + biasv[_m][_r];                    \
        if (_hv) out[(size_t)(b0 + _n) * ((size_t)COUT * H_)                  \
                     + (size_t)_o * H_ + _h] = _v;                            \
    }                                                                         \
} while (0)

#define VW(n)  asm volatile("s_waitcnt vmcnt(" #n ") lgkmcnt(0)" ::: "memory")
#define BAR()  __builtin_amdgcn_s_barrier()

    floatx4 acc[2][4];

    SGH(0, 0, buf0);                                   // [8L]
    VW(0);  BAR(); SGH(0, 1, buf1); CA(acc, buf0);     // P0: t0/h0
    VW(0);  BAR(); SGH(1, 0, buf0); CB(acc, buf1);     // P1: t0/h1
    EPI(0, acc, false);                                //   +32S -> [8L][32S]
    VW(32); BAR(); SGH(1, 1, buf1); CA(acc, buf0);     // P2: retire 8L only
    VW(0);  BAR(); SGH(2, 0, buf0); CB(acc, buf1);     // P3: drains aged 32S
    EPI(1, acc, false);
    VW(32); BAR(); SGH(2, 1, buf1); CA(acc, buf0);     // P4
    VW(0);  BAR(); SGH(3, 0, buf0); CB(acc, buf1);     // P5
    EPI(2, acc, false);
    VW(32); BAR(); SGH(3, 1, buf1); CA(acc, buf0);     // P6
    VW(0);  BAR();                  CB(acc, buf1);     // P7
    EPI(3, acc, bnd);                                  //   drains at endpgm

#undef SGH
#undef CA
#undef CB
#undef EPI
#undef VW
#undef BAR
}

extern "C" void kernel_launch(void* const* d_in, const int* in_sizes, int n_in,
                              void* d_out, int out_size, void* d_ws, size_t ws_size,
                              hipStream_t stream) {
    const float* x    = (const float*)d_in[0];   // f32 [64,64,1855]
    const int*   nbr  = (const int*)d_in[1];     // int32 [1855,6]
    const float* wc   = (const float*)d_in[2];   // f32 [128,64]
    const float* wn   = (const float*)d_in[3];   // f32 [128,64,6]
    const float* bias = (const float*)d_in[4];   // f32 [128]

    u16*   xt3    = (u16*)d_ws;
    u16*   wp     = (u16*)((char*)d_ws + WP_OFF);
    float* cInvG  = (float*)((char*)d_ws + CINV_OFF);
    u32*   zeroPg = (u32*)((char*)d_ws + ZERO_OFF);
    u32*   srcOff = (u32*)((char*)d_ws + SRCOFF_OFF);

    k_prep<<<dim3(29, 65), dim3(256), 0, stream>>>(
        x, wc, wn, nbr, xt3, wp, cInvG, zeroPg, srcOff);
    k_main<<<dim3(464), dim3(256), 0, stream>>>(
        xt3, wp, bias, cInvG, srcOff, (float*)d_out);
}

// Round 7
// 141.700 us; speedup vs baseline: 1.5538x; 1.0167x over previous
//
#include <hip/hip_runtime.h>
#include <stdint.h>

typedef __bf16 bf16x8 __attribute__((ext_vector_type(8)));
typedef float floatx4 __attribute__((ext_vector_type(4)));
typedef float floatx4u __attribute__((ext_vector_type(4), aligned(4)));
typedef unsigned int u32x4 __attribute__((ext_vector_type(4)));
typedef unsigned short u16;
typedef unsigned int u32;

#define CIN   64
#define COUT  128
#define H_    1855
#define KNB   6
#define KTOT  448      // (1+KNB)*CIN
#define NSTEPS 14      // KTOT / 32

// N=32 half-tile buffer (proven R3 geometry): 16 hl rows; row = [s:4][b:2]
// [c:64]*2B = 1024 B + 16 pad = 1040 (b128 B-frag reads 2-way on banks).
// 2 ping-pong buffers = 33280 B + 2 KB srcOff table = 35328 -> 4 blocks/CU.
#define HROW   1040
#define HBUFSZ 16640   // 16 * HROW
#define STAB_OFF (2 * HBUFSZ)

// ws layout (bytes)
#define WP_OFF     ((size_t)H_ * 4096 * 2)                 // xt3: bf16 [h][4096]
#define CINV_OFF   (WP_OFF + (size_t)COUT * KTOT * 2)      // f32 [H]
#define SRCOFF_OFF (CINV_OFF + 7424)                       // u32 [H][8] resolved row offsets
#define ZROW_OFF   (SRCOFF_OFF + 59392)                    // 8-KB zero row (fake xt3 row)

#define PIN4(v) asm volatile("" : "+v"(v))

typedef __attribute__((address_space(1))) unsigned int as1_u32;
typedef __attribute__((address_space(3))) unsigned int as3_u32;
static __device__ __forceinline__ void ld16_to_lds(const void* g, void* l) {
    __builtin_amdgcn_global_load_lds((const as1_u32*)g, (as3_u32*)l, 16, 0, 0);
}

static __device__ inline u16 f32_to_bf16(float f) {
    u32 u = __float_as_uint(f);
    u32 r = (u + 0x7FFFu + ((u >> 16) & 1u)) >> 16;
    return (u16)r;
}

// ---- K1 (fused): transpose x f32 [bc][h] -> xt3 bf16 [h][bc], plus
// weight-pack / inverse-counts / zero-row / RESOLVED gather-offset table
// (invalid neighbor -> ZROW_OFF, so k_main staging needs no select).
__global__ __launch_bounds__(256) void k_prep(const float* __restrict__ x,
                                              const float* __restrict__ wc,
                                              const float* __restrict__ wn,
                                              const int* __restrict__ nbr,
                                              u16* __restrict__ xt3,
                                              u16* __restrict__ wp,
                                              float* __restrict__ cInvG,
                                              u32* __restrict__ srcOff2,
                                              u32* __restrict__ zrow) {
    int tid = threadIdx.x;
    if (blockIdx.y == 64) {            // ---- pack stripe (29 blocks, strided)
        for (int tg = blockIdx.x * 256 + tid; tg < COUT * KTOT; tg += 29 * 256) {
            if (tg < 2048) zrow[tg] = 0u;            // 8-KB zero row
            if (tg < H_) {
                int cnt = 1;
#pragma unroll
                for (int j = 0; j < KNB; ++j) cnt += (nbr[tg * KNB + j] >= 0) ? 1 : 0;
                cInvG[tg] = 1.0f / (float)cnt;
            }
            if (tg < H_ * 8) {
                int h = tg >> 3, s = tg & 7;
                u32 e;
                if (s == 0) e = (u32)h * 8192u;
                else if (s <= 6) {
                    int n = nbr[h * KNB + (s - 1)];
                    e = (n >= 0) ? (u32)n * 8192u : (u32)ZROW_OFF;
                } else e = (u32)ZROW_OFF;
                srcOff2[tg] = e;
            }
            int o = tg / KTOT;
            int rem = tg - o * KTOT;
            int s = rem >> 6, c = rem & 63;
            float v = (s == 0) ? wc[o * CIN + c]
                               : wn[(o * CIN + c) * KNB + (s - 1)];
            wp[tg] = f32_to_bf16(v);
        }
        return;
    }
    // ---- transpose stripe: tile = u32 (bc even|odd packed), stride 34
    __shared__ u32 t32[64][34];
    int h0  = blockIdx.x * 64;
    int bc0 = blockIdx.y * 64;
    int lh = tid & 15;                 // h-quad (4 h per thread)
    int rq = tid >> 4;                 // 0..15 rowpair sub-index
    bool safe = (h0 + 64 <= H_);
#pragma unroll
    for (int it = 0; it < 2; ++it) {
        int rp = it * 16 + rq;         // rowpair 0..31 -> rows 2rp, 2rp+1
        size_t r0 = (size_t)(bc0 + rp * 2) * H_;
        size_t r1 = r0 + H_;
        int h = h0 + lh * 4;
        u32 p[4];
        if (safe) {
            floatx4u f0 = *(const floatx4u*)(x + r0 + h);
            floatx4u f1 = *(const floatx4u*)(x + r1 + h);
#pragma unroll
            for (int j = 0; j < 4; ++j)
                p[j] = (u32)f32_to_bf16(f0[j]) | ((u32)f32_to_bf16(f1[j]) << 16);
        } else {
#pragma unroll
            for (int j = 0; j < 4; ++j) {
                int hh = h + j;
                u16 a = 0, b = 0;
                if (hh < H_) { a = f32_to_bf16(x[r0 + hh]); b = f32_to_bf16(x[r1 + hh]); }
                p[j] = (u32)a | ((u32)b << 16);
            }
        }
#pragma unroll
        for (int j = 0; j < 4; ++j) t32[lh * 4 + j][rp] = p[j];
    }
    __syncthreads();
    int bg = tid & 7;                  // bc-octet
    int hb = tid >> 3;                 // 0..31
#pragma unroll
    for (int ii = 0; ii < 2; ++ii) {
        int hl = ii * 32 + hb;
        int hh = h0 + hl;
        uint2 qa = *(const uint2*)&t32[hl][bg * 4];
        uint2 qb = *(const uint2*)&t32[hl][bg * 4 + 2];
        u32x4 q = {qa.x, qa.y, qb.x, qb.y};
        if (hh < H_)
            *(u32x4*)(xt3 + (size_t)hh * 4096 + bc0 + bg * 8) = q;
    }
}

// ---- K3: main gather-GEMM, 16 waves/CU occupancy design ------------------
// grid = 1856 = 29 hs x 32 b-pairs x 2 om-halves (XCD = gbl&7 -> 8 b's =
// 1.9 MB xt3 slice L2-hot). Block: 4 waves, M=16/wave (afrag 56 VGPR — the
// key change vs R1/R3's 112), M=64/block, N=32 (2b x 16h). Per-wave live
// ~95 regs -> fits the 128 cap of (256,4) -> 4 blocks/CU, 16 waves/CU (2x
// R3's 8). srcOff lives in a 2-KB LDS table (kills the 32-reg offs array
// that blew R2/R4's budget); invalid neighbors pre-resolved to a zero row.
__global__ __launch_bounds__(256, 4) void k_main(const u16* __restrict__ xt3,
                                                 const u16* __restrict__ wp,
                                                 const float* __restrict__ bias,
                                                 const float* __restrict__ cInvG,
                                                 const u32* __restrict__ srcOff2,
                                                 float* __restrict__ out) {
    __shared__ __align__(16) char LDS[2 * HBUFSZ + 2048];

    int tid  = threadIdx.x;
    int gbl  = blockIdx.x;
    int bp   = gbl & 31;          // b-pair; XCD = gbl&7
    int rest = gbl >> 5;          // 0..57
    int hs   = rest >> 1;         // 0..28
    int om   = rest & 1;          // o-half
    int b0   = bp * 2;
    int h0   = hs * 64;
    int om0  = om * 64;

    int lane = tid & 63;
    int wave = tid >> 6;          // 0..3
    int col  = lane & 15;
    int quad = lane >> 4;
    int lane16 = lane & 15;
    int ssub = lane >> 4;         // s sub-index within a staging instr
    int bl   = lane16 >> 3;       // b low bit
    int chunk = lane16 & 7;       // 16-B c-chunk
    int mrow = om0 + wave * 16;   // wave's 16 output rows

    const char* xb = (const char*)xt3;   // == d_ws base; all offsets relative
    u32* sTab = (u32*)(LDS + STAB_OFF);  // [64 h][8 s] resolved row offsets

    // srcOff table -> LDS (512 u32; guard the 8 entries past H_*8 at hs=28)
    {
        int j0 = tid * 2;
        int g0 = h0 * 8 + j0;
        u32 e0 = (g0 < H_ * 8) ? srcOff2[g0] : (u32)ZROW_OFF;
        u32 e1 = (g0 + 1 < H_ * 8) ? srcOff2[g0 + 1] : (u32)ZROW_OFF;
        sTab[j0] = e0;
        sTab[j0 + 1] = e1;
    }

    // A fragments (weights): wave's 16 rows, A[m=col][k=quad*8+j]; 56 VGPR.
    u32x4 afrag[NSTEPS];
    {
        int o = mrow + col;
#pragma unroll
        for (int kk = 0; kk < NSTEPS; ++kk)
            afrag[kk] = *(const u32x4*)(wp + o * KTOT + kk * 32 + quad * 8);
    }
#pragma unroll
    for (int kk = 0; kk < NSTEPS; ++kk) PIN4(afrag[kk]);

    float biasv[4];
#pragma unroll
    for (int r = 0; r < 4; ++r) biasv[r] = bias[mrow + quad * 4 + r];

    float icv[4];
#pragma unroll
    for (int t = 0; t < 4; ++t) {
        int hic = h0 + t * 16 + col;
        icv[t] = cInvG[hic < H_ ? hic : 0];
    }

    u32 colOff = (u32)((b0 + bl) * 128 + chunk * 16);
    int rb = col * HROW + quad * 16;
    char* buf0 = LDS;
    char* buf1 = LDS + HBUFSZ;
    bool bnd = (hs == 28);

    __syncthreads();   // table visible; drains all prologue vm loads (vmcnt=0)

// Stage half-tile (t,hf) into bufp: 4 instrs/wave (rows wave*4+i). Per-lane
// source = LDS-table row offset (per-lane s = hf*4+ssub) + colOff.
#define SGH(t, hf, bufp) do {                                                 \
    _Pragma("unroll")                                                         \
    for (int _i = 0; _i < 4; ++_i) {                                          \
        int _hl = wave * 4 + _i;                                              \
        u32 _e = sTab[((t) * 16 + _hl) * 8 + (hf) * 4 + ssub];                \
        ld16_to_lds(xb + _e + colOff, (bufp) + _hl * HROW);                   \
    }                                                                         \
} while (0)

#define CA(bufp) do {  /* k-steps 0..7 (s0..3), zero-init */                  \
    acc[0] = (floatx4){0.0f, 0.0f, 0.0f, 0.0f};                               \
    acc[1] = (floatx4){0.0f, 0.0f, 0.0f, 0.0f};                               \
    __builtin_amdgcn_s_setprio(1);                                            \
    _Pragma("unroll")                                                         \
    for (int kk = 0; kk < 8; ++kk) {                                          \
        int _ko = (kk >> 1) * 256 + (kk & 1) * 64;                            \
        bf16x8 bfa = *(const bf16x8*)((bufp) + rb + _ko);                     \
        bf16x8 bfb = *(const bf16x8*)((bufp) + rb + 128 + _ko);               \
        bf16x8 a = __builtin_bit_cast(bf16x8, afrag[kk]);                     \
        acc[0] = __builtin_amdgcn_mfma_f32_16x16x32_bf16(a, bfa, acc[0], 0, 0, 0); \
        acc[1] = __builtin_amdgcn_mfma_f32_16x16x32_bf16(a, bfb, acc[1], 0, 0, 0); \
    }                                                                         \
    __builtin_amdgcn_s_setprio(0);                                            \
} while (0)

#define CB(bufp) do {  /* k-steps 8..13 (s4..6), accumulate */                \
    __builtin_amdgcn_s_setprio(1);                                            \
    _Pragma("unroll")                                                         \
    for (int kk = 8; kk < 14; ++kk) {                                         \
        int _k2 = kk - 8;                                                     \
        int _ko = (_k2 >> 1) * 256 + (_k2 & 1) * 64;                          \
        bf16x8 bfa = *(const bf16x8*)((bufp) + rb + _ko);                     \
        bf16x8 bfb = *(const bf16x8*)((bufp) + rb + 128 + _ko);               \
        bf16x8 a = __builtin_bit_cast(bf16x8, afrag[kk]);                     \
        acc[0] = __builtin_amdgcn_mfma_f32_16x16x32_bf16(a, bfa, acc[0], 0, 0, 0); \
        acc[1] = __builtin_amdgcn_mfma_f32_16x16x32_bf16(a, bfb, acc[1], 0, 0, 0); \
    }                                                                         \
    __builtin_amdgcn_s_setprio(0);                                            \
} while (0)

// Per-tile epilogue: 8 direct stores/lane (16 col lanes = 64-B segments).
// Final epilogue (uncounted) masks the single ragged lane at h=1855.
#define EPI(t, BND) do {                                                      \
    int _h = h0 + (t) * 16 + col;                                             \
    float _ic = icv[t];                                                       \
    bool _hv = !(BND) || (_h < H_);                                           \
    _Pragma("unroll") for (int _n = 0; _n < 2; ++_n)                          \
    _Pragma("unroll") for (int _r = 0; _r < 4; ++_r) {                        \
        int _o = mrow + quad * 4 + _r;                                        \
        float _v = acc[_n][_r] * _ic + biasv[_r];                             \
        if (_hv) out[(size_t)(b0 + _n) * ((size_t)COUT * H_)                  \
                     + (size_t)_o * H_ + _h] = _v;                            \
    }                                                                         \
} while (0)

#define VW(n)  asm volatile("s_waitcnt vmcnt(" #n ") lgkmcnt(0)" ::: "memory")
#define BAR()  __builtin_amdgcn_s_barrier()

    floatx4 acc[2];

    // Ladder (per-wave FIFO; 4L per SGH, 8S per EPI). Stores are >=2 phases
    // old at any drain; loads aged 1 phase (R3-proven discipline).
    SGH(0, 0, buf0);                                   // [4L]
    VW(0); BAR(); SGH(0, 1, buf1); CA(buf0);           // P0: t0/h0
    VW(0); BAR(); SGH(1, 0, buf0); CB(buf1);           // P1: t0/h1
    EPI(0, false);                                     //   [4L][8S]
    VW(8); BAR(); SGH(1, 1, buf1); CA(buf0);           // P2: retire 4L only
    VW(0); BAR(); SGH(2, 0, buf0); CB(buf1);           // P3: drains 8S (aged 2)
    EPI(1, false);
    VW(8); BAR(); SGH(2, 1, buf1); CA(buf0);           // P4
    VW(0); BAR(); SGH(3, 0, buf0); CB(buf1);           // P5
    EPI(2, false);
    VW(8); BAR(); SGH(3, 1, buf1); CA(buf0);           // P6
    VW(0); BAR();                  CB(buf1);           // P7
    EPI(3, bnd);                                       //   drains at endpgm

#undef SGH
#undef CA
#undef CB
#undef EPI
#undef VW
#undef BAR
}

extern "C" void kernel_launch(void* const* d_in, const int* in_sizes, int n_in,
                              void* d_out, int out_size, void* d_ws, size_t ws_size,
                              hipStream_t stream) {
    const float* x    = (const float*)d_in[0];   // f32 [64,64,1855]
    const int*   nbr  = (const int*)d_in[1];     // int32 [1855,6]
    const float* wc   = (const float*)d_in[2];   // f32 [128,64]
    const float* wn   = (const float*)d_in[3];   // f32 [128,64,6]
    const float* bias = (const float*)d_in[4];   // f32 [128]

    u16*   xt3    = (u16*)d_ws;
    u16*   wp     = (u16*)((char*)d_ws + WP_OFF);
    float* cInvG  = (float*)((char*)d_ws + CINV_OFF);
    u32*   srcOff = (u32*)((char*)d_ws + SRCOFF_OFF);
    u32*   zrow   = (u32*)((char*)d_ws + ZROW_OFF);

    k_prep<<<dim3(29, 65), dim3(256), 0, stream>>>(
        x, wc, wn, nbr, xt3, wp, cInvG, srcOff, zrow);
    k_main<<<dim3(1856), dim3(256), 0, stream>>>(
        xt3, wp, bias, cInvG, srcOff, (float*)d_out);
}

// Round 8
// 126.586 us; speedup vs baseline: 1.7393x; 1.1194x over previous
//
#include <hip/hip_runtime.h>
#include <stdint.h>

typedef __bf16 bf16x8 __attribute__((ext_vector_type(8)));
typedef float floatx4 __attribute__((ext_vector_type(4)));
typedef float floatx4u __attribute__((ext_vector_type(4), aligned(4)));
typedef unsigned int u32x4 __attribute__((ext_vector_type(4)));
typedef unsigned short u16;
typedef unsigned int u32;

#define CIN   64
#define COUT  128
#define H_    1855
#define KNB   6
#define KTOT  448      // (1+KNB)*CIN
#define NSTEPS 14      // KTOT / 32

// Half-buffer geometry (R3-verified): half-tile = 16 hl rows x 4 s-slots.
// Row = 4*256+16 pad = 1040 B. 4 rotating half-buffers.
#define HROW   1040
#define HBUFSZ 16640   // 16 * HROW

// ws layout (bytes)
#define WP_OFF     ((size_t)H_ * 4096 * 2)                 // xt3: bf16 [h][4096]
#define CINV_OFF   (WP_OFF + (size_t)COUT * KTOT * 2)
#define ZERO_OFF   (CINV_OFF + 7424)                       // 512-B zero page (256-B aligned)
#define SRCOFF_OFF (ZERO_OFF + 1024)                       // u32 [H][8] gather row offsets
#define INVOFF 0xFFFFFFFFu

#define PIN4(v) asm volatile("" : "+v"(v))

typedef __attribute__((address_space(1))) unsigned int as1_u32;
typedef __attribute__((address_space(3))) unsigned int as3_u32;
static __device__ __forceinline__ void ld16_to_lds(const void* g, void* l) {
    __builtin_amdgcn_global_load_lds((const as1_u32*)g, (as3_u32*)l, 16, 0, 0);
}

static __device__ inline u16 f32_to_bf16(float f) {
    u32 u = __float_as_uint(f);
    u32 r = (u + 0x7FFFu + ((u >> 16) & 1u)) >> 16;
    return (u16)r;
}

// ---- K1 (fused): transpose x f32 [bc][h] -> xt3 bf16 [h][bc], plus
// weight-pack / inverse-counts / zero-page / gather-offset table in the
// blockIdx.y==64 stripe. (Verified R3/R4/R6/R7.)
__global__ __launch_bounds__(256) void k_prep(const float* __restrict__ x,
                                              const float* __restrict__ wc,
                                              const float* __restrict__ wn,
                                              const int* __restrict__ nbr,
                                              u16* __restrict__ xt3,
                                              u16* __restrict__ wp,
                                              float* __restrict__ cInvG,
                                              u32* __restrict__ zeroPg,
                                              u32* __restrict__ srcOff) {
    int tid = threadIdx.x;
    if (blockIdx.y == 64) {            // ---- pack stripe (29 blocks, strided)
        for (int tg = blockIdx.x * 256 + tid; tg < COUT * KTOT; tg += 29 * 256) {
            if (tg < 128) zeroPg[tg] = 0u;           // 512-B zero page
            if (tg < H_) {
                int cnt = 1;
#pragma unroll
                for (int j = 0; j < KNB; ++j) cnt += (nbr[tg * KNB + j] >= 0) ? 1 : 0;
                cInvG[tg] = 1.0f / (float)cnt;
            }
            if (tg < H_ * 8) {
                int h = tg >> 3, s = tg & 7;
                u32 e;
                if (s == 0) e = (u32)h * 8192u;
                else if (s <= 6) {
                    int n = nbr[h * KNB + (s - 1)];
                    e = (n >= 0) ? (u32)n * 8192u : INVOFF;
                } else e = INVOFF;
                srcOff[tg] = e;
            }
            int o = tg / KTOT;
            int rem = tg - o * KTOT;
            int s = rem >> 6, c = rem & 63;
            float v = (s == 0) ? wc[o * CIN + c]
                               : wn[(o * CIN + c) * KNB + (s - 1)];
            wp[tg] = f32_to_bf16(v);
        }
        return;
    }
    // ---- transpose stripe: tile = u32 (bc even|odd packed), stride 34
    __shared__ u32 t32[64][34];
    int h0  = blockIdx.x * 64;
    int bc0 = blockIdx.y * 64;
    int lh = tid & 15;                 // h-quad (4 h per thread)
    int rq = tid >> 4;                 // 0..15 rowpair sub-index
    bool safe = (h0 + 64 <= H_);
#pragma unroll
    for (int it = 0; it < 2; ++it) {
        int rp = it * 16 + rq;         // rowpair 0..31 -> rows 2rp, 2rp+1
        size_t r0 = (size_t)(bc0 + rp * 2) * H_;
        size_t r1 = r0 + H_;
        int h = h0 + lh * 4;
        u32 p[4];
        if (safe) {
            floatx4u f0 = *(const floatx4u*)(x + r0 + h);
            floatx4u f1 = *(const floatx4u*)(x + r1 + h);
#pragma unroll
            for (int j = 0; j < 4; ++j)
                p[j] = (u32)f32_to_bf16(f0[j]) | ((u32)f32_to_bf16(f1[j]) << 16);
        } else {
#pragma unroll
            for (int j = 0; j < 4; ++j) {
                int hh = h + j;
                u16 a = 0, b = 0;
                if (hh < H_) { a = f32_to_bf16(x[r0 + hh]); b = f32_to_bf16(x[r1 + hh]); }
                p[j] = (u32)a | ((u32)b << 16);
            }
        }
#pragma unroll
        for (int j = 0; j < 4; ++j) t32[lh * 4 + j][rp] = p[j];
    }
    __syncthreads();
    int bg = tid & 7;                  // bc-octet
    int hb = tid >> 3;                 // 0..31
#pragma unroll
    for (int ii = 0; ii < 2; ++ii) {
        int hl = ii * 32 + hb;
        int hh = h0 + hl;
        uint2 qa = *(const uint2*)&t32[hl][bg * 4];
        uint2 qb = *(const uint2*)&t32[hl][bg * 4 + 2];
        u32x4 q = {qa.x, qa.y, qb.x, qb.y};
        if (hh < H_)
            *(u32x4*)(xt3 + (size_t)hh * 4096 + bc0 + bg * 8) = q;
    }
}

// ---- K3: PERSISTENT gather-GEMM ------------------------------------------
// grid = 512 = 32 bp x 16 slots — exactly 2 blocks/CU, ALL co-resident from
// t=0, so the round-robin XCD assignment (XCD = gbl&7 = bp&7) holds for the
// WHOLE kernel: each XCD keeps its 4 bp-slices (1.9 MB of xt3) L2-hot and
// the ~7x temporal gather reuse across hs-supertiles becomes L2 hits instead
// of round-2 L3 hits. Slot j processes hs = j and j+16 (j<=12), pinned bp.
// Inner ladder = R3-verified depth-3 / 4-buffer / counted-vmcnt, VERBATIM;
// conservative VW(0)+BAR seam between hs iterations.
__global__ __launch_bounds__(256, 2) void k_main(const u16* __restrict__ xt3,
                                                 const u16* __restrict__ wp,
                                                 const float* __restrict__ bias,
                                                 const float* __restrict__ cInvG,
                                                 const u32* __restrict__ srcOff,
                                                 float* __restrict__ out) {
    __shared__ __align__(16) char LDS[4 * HBUFSZ];

    int tid  = threadIdx.x;
    int gbl  = blockIdx.x;
    int bp   = gbl & 31;          // b-pair, FIXED for block lifetime; XCD = bp&7
    int slot = gbl >> 5;          // 0..15
    int b0   = bp * 2;

    int lane = tid & 63;
    int wave = tid >> 6;          // 0..3
    int col  = lane & 15;
    int quad = lane >> 4;
    int m0w  = wave * 32;
    int lane16 = lane & 15;
    int ssub = lane >> 4;
    int bl   = lane16 >> 3;
    int chunk = lane16 & 7;

    const char* xb = (const char*)xt3;   // == d_ws base; all offsets relative

    // A fragments (weights): A[m=col][k=quad*8+j]; 112 regs, pinned.
    // Loaded ONCE per block (persistent amortization).
    u32x4 afrag[2][NSTEPS];
#pragma unroll
    for (int mt = 0; mt < 2; ++mt) {
        int o = m0w + mt * 16 + col;
#pragma unroll
        for (int kk = 0; kk < NSTEPS; ++kk)
            afrag[mt][kk] = *(const u32x4*)(wp + o * KTOT + kk * 32 + quad * 8);
    }
#pragma unroll
    for (int mt = 0; mt < 2; ++mt)
#pragma unroll
        for (int kk = 0; kk < NSTEPS; ++kk)
            PIN4(afrag[mt][kk]);

    float biasv[2][4];
#pragma unroll
    for (int mt = 0; mt < 2; ++mt)
#pragma unroll
        for (int r = 0; r < 4; ++r)
            biasv[mt][r] = bias[m0w + mt * 16 + quad * 4 + r];

    u32 colOff = (u32)((b0 + bl) * 128 + chunk * 16);
    u32 zOff   = (u32)ZERO_OFF + (u32)(lane16 * 16);

    int rb0 = col * HROW + quad * 16;
    int rb1 = rb0 + 128;
    char* bufA0 = LDS;
    char* bufA1 = LDS + HBUFSZ;
    char* bufA2 = LDS + 2 * HBUFSZ;
    char* bufA3 = LDS + 3 * HBUFSZ;

#define SGH(t, sg, bufp) do {                                                 \
    char* _d = (bufp) + (wave * 4) * HROW;                                    \
    _Pragma("unroll")                                                         \
    for (int _i = 0; _i < 4; ++_i)                                            \
        ld16_to_lds(xb + offs[t][sg][_i], _d + _i * HROW);                    \
} while (0)

#define CA(accv, bufp) do {  /* k-steps 0..7, zero-init */                    \
    _Pragma("unroll") for (int _m = 0; _m < 2; ++_m)                          \
    _Pragma("unroll") for (int _n = 0; _n < 2; ++_n)                          \
        accv[_m][_n] = (floatx4){0.0f, 0.0f, 0.0f, 0.0f};                     \
    __builtin_amdgcn_s_setprio(1);                                            \
    _Pragma("unroll")                                                         \
    for (int kk = 0; kk < 8; ++kk) {                                          \
        int koff = (kk >> 1) * 256 + (kk & 1) * 64;                           \
        bf16x8 bfa = *(const bf16x8*)((bufp) + rb0 + koff);                   \
        bf16x8 bfb = *(const bf16x8*)((bufp) + rb1 + koff);                   \
        bf16x8 a0 = __builtin_bit_cast(bf16x8, afrag[0][kk]);                 \
        bf16x8 a1 = __builtin_bit_cast(bf16x8, afrag[1][kk]);                 \
        accv[0][0] = __builtin_amdgcn_mfma_f32_16x16x32_bf16(a0, bfa, accv[0][0], 0, 0, 0); \
        accv[1][0] = __builtin_amdgcn_mfma_f32_16x16x32_bf16(a1, bfa, accv[1][0], 0, 0, 0); \
        accv[0][1] = __builtin_amdgcn_mfma_f32_16x16x32_bf16(a0, bfb, accv[0][1], 0, 0, 0); \
        accv[1][1] = __builtin_amdgcn_mfma_f32_16x16x32_bf16(a1, bfb, accv[1][1], 0, 0, 0); \
    }                                                                         \
    __builtin_amdgcn_s_setprio(0);                                            \
} while (0)

#define CB(accv, bufp) do {  /* k-steps 8..13, accumulate */                  \
    __builtin_amdgcn_s_setprio(1);                                            \
    _Pragma("unroll")                                                         \
    for (int kk = 8; kk < 14; ++kk) {                                         \
        int koff = ((kk - 8) >> 1) * 256 + (kk & 1) * 64;                     \
        bf16x8 bfa = *(const bf16x8*)((bufp) + rb0 + koff);                   \
        bf16x8 bfb = *(const bf16x8*)((bufp) + rb1 + koff);                   \
        bf16x8 a0 = __builtin_bit_cast(bf16x8, afrag[0][kk]);                 \
        bf16x8 a1 = __builtin_bit_cast(bf16x8, afrag[1][kk]);                 \
        accv[0][0] = __builtin_amdgcn_mfma_f32_16x16x32_bf16(a0, bfa, accv[0][0], 0, 0, 0); \
        accv[1][0] = __builtin_amdgcn_mfma_f32_16x16x32_bf16(a1, bfa, accv[1][0], 0, 0, 0); \
        accv[0][1] = __builtin_amdgcn_mfma_f32_16x16x32_bf16(a0, bfb, accv[0][1], 0, 0, 0); \
        accv[1][1] = __builtin_amdgcn_mfma_f32_16x16x32_bf16(a1, bfb, accv[1][1], 0, 0, 0); \
    }                                                                         \
    __builtin_amdgcn_s_setprio(0);                                            \
} while (0)

// Pair epilogue via wave-private E overlay in a freed half-buffer: writes
// XOR-swizzled by (o&7), conflict-free b128 readback, 8 float4 stores/lane
// (128-B segments). BND (final epilogue of final hs only) masks the ragged
// float — uncounted position, ladder counts stay exact.
#define EPI(pp, a0v, a1v, Ebuf, BND) do {                                     \
    float* _E = (float*)((Ebuf) + (wave * 4) * HROW);                         \
    int _o8 = lane >> 3, _h4 = lane & 7;                                      \
    _Pragma("unroll")                                                         \
    for (int _nt = 0; _nt < 2; ++_nt) {                                       \
        asm volatile("s_waitcnt lgkmcnt(0)" ::: "memory");                    \
        _Pragma("unroll") for (int _mt = 0; _mt < 2; ++_mt)                   \
        _Pragma("unroll") for (int _r = 0; _r < 4; ++_r) {                    \
            int _ol = _mt * 16 + quad * 4 + _r;                               \
            int _x0 = ((col >> 2) ^ (_ol & 7));                               \
            int _x1 = (((16 + col) >> 2) ^ (_ol & 7));                        \
            _E[_ol * 32 + (_x0 << 2) + (col & 3)] =                           \
                a0v[_mt][_nt][_r] * icv[(pp) * 2]     + biasv[_mt][_r];       \
            _E[_ol * 32 + (_x1 << 2) + (col & 3)] =                           \
                a1v[_mt][_nt][_r] * icv[(pp) * 2 + 1] + biasv[_mt][_r];       \
        }                                                                     \
        asm volatile("s_waitcnt lgkmcnt(0)" ::: "memory");                    \
        _Pragma("unroll")                                                     \
        for (int _q = 0; _q < 4; ++_q) {                                      \
            int _ol = _q * 8 + _o8;                                           \
            floatx4 _v = *(const floatx4*)(_E + _ol * 32 + ((_h4 ^ (_ol & 7)) << 2)); \
            int _hh = h0 + (pp) * 32 + _h4 * 4;                               \
            float* _dst = out + (size_t)(b0 + _nt) * ((size_t)COUT * H_)      \
                        + (size_t)(m0w + _ol) * H_ + _hh;                     \
            if (!(BND)) {                                                     \
                *(floatx4u*)_dst = _v;                                        \
            } else {                                                          \
                _Pragma("unroll") for (int _e = 0; _e < 4; ++_e)              \
                    if (_hh + _e < H_) _dst[_e] = _v[_e];                     \
            }                                                                 \
        }                                                                     \
    }                                                                         \
} while (0)

#define VW(n)  asm volatile("s_waitcnt vmcnt(" #n ") lgkmcnt(0)" ::: "memory")
#define BAR()  __builtin_amdgcn_s_barrier()

    floatx4 acc0[2][2], acc1[2][2];
    int nhs = (slot + 16 <= 28) ? 2 : 1;

    for (int q = 0; q < nhs; ++q) {
        int hs = slot + q * 16;       // 0..28
        int h0 = hs * 64;
        bool bnd = (hs == 28);

        // Per-hs setup: icv + staging offsets (vm loads; retired by the
        // compiler's data-dep waits before SGH issue, and in any case older
        // than everything the ladder's counted waits examine).
        float icv[4];
#pragma unroll
        for (int t = 0; t < 4; ++t) {
            int hic = h0 + t * 16 + col;
            icv[t] = cInvG[hic < H_ ? hic : 0];
        }
        u32 offs[4][2][4];
#pragma unroll
        for (int t = 0; t < 4; ++t)
#pragma unroll
            for (int sg = 0; sg < 2; ++sg)
#pragma unroll
                for (int i = 0; i < 4; ++i) {
                    int hh = h0 + t * 16 + wave * 4 + i;
                    int s  = sg * 4 + ssub;
                    u32 e = (hh < H_) ? srcOff[hh * 8 + s] : INVOFF;
                    offs[t][sg][i] = (e == INVOFF) ? zOff : (e + colOff);
                }

        // ---- R3-verified ladder (verbatim) ----
        SGH(0, 0, bufA0);                 // S0
        SGH(0, 1, bufA1);                 // S1
        SGH(1, 0, bufA2);                 // S2

        VW(8);  BAR(); SGH(1, 1, bufA3);  CA(acc0, bufA0);   // ph0
        VW(8);  BAR(); SGH(2, 0, bufA0);  CB(acc0, bufA1);   // ph1
        VW(8);  BAR(); SGH(2, 1, bufA1);  CA(acc1, bufA2);   // ph2
        VW(8);  BAR();                    CB(acc1, bufA3);   // ph3
        EPI(0, acc0, acc1, bufA2, false);
        VW(12); BAR(); SGH(3, 0, bufA2);  CA(acc0, bufA0);   // ph4
        VW(12); BAR(); SGH(3, 1, bufA3);  CB(acc0, bufA1);   // ph5
        VW(4);  BAR();                    CA(acc1, bufA2);   // ph6
        VW(0);  BAR();                    CB(acc1, bufA3);   // ph7
        EPI(1, acc0, acc1, bufA2, bnd);

        // Conservative seam: drain everything (incl. EPI(1) stores) and
        // resync before the next hs iteration reuses the buffers.
        if (q + 1 < nhs) { VW(0); BAR(); }
    }

#undef SGH
#undef CA
#undef CB
#undef EPI
#undef VW
#undef BAR
}

extern "C" void kernel_launch(void* const* d_in, const int* in_sizes, int n_in,
                              void* d_out, int out_size, void* d_ws, size_t ws_size,
                              hipStream_t stream) {
    const float* x    = (const float*)d_in[0];   // f32 [64,64,1855]
    const int*   nbr  = (const int*)d_in[1];     // int32 [1855,6]
    const float* wc   = (const float*)d_in[2];   // f32 [128,64]
    const float* wn   = (const float*)d_in[3];   // f32 [128,64,6]
    const float* bias = (const float*)d_in[4];   // f32 [128]

    u16*   xt3    = (u16*)d_ws;
    u16*   wp     = (u16*)((char*)d_ws + WP_OFF);
    float* cInvG  = (float*)((char*)d_ws + CINV_OFF);
    u32*   zeroPg = (u32*)((char*)d_ws + ZERO_OFF);
    u32*   srcOff = (u32*)((char*)d_ws + SRCOFF_OFF);

    k_prep<<<dim3(29, 65), dim3(256), 0, stream>>>(
        x, wc, wn, nbr, xt3, wp, cInvG, zeroPg, srcOff);
    k_main<<<dim3(512), dim3(256), 0, stream>>>(
        xt3, wp, bias, cInvG, srcOff, (float*)d_out);
}